// Round 8
// baseline (17.998 us; speedup 1.0000x reference)
//
#include <hip/hip_runtime.h>

#define NQ 12
#define DIM 4096
#define BLK 256

typedef float v2f __attribute__((ext_vector_type(2)));

// gray-to-binary (== CNOT chain relabel): bit i of result = XOR of bits >= i.
__host__ __device__ constexpr int igrayc(int v) {
    v ^= v >> 1; v ^= v >> 2; v ^= v >> 4; v ^= v >> 8;
    return v & (DIM - 1);
}
// binary-to-gray composed k times: g^1=v^(v>>1), g^2=v^(v>>2), g^3=g^1∘g^2
__host__ __device__ constexpr int gkf(int v, int k) {
    if (k == 1) v ^= v >> 1;
    else if (k == 2) v ^= v >> 2;
    else { v ^= v >> 2; v ^= v >> 1; }
    return v;
}
// LDS swizzle (involution) — bank-pair = low4(sig); rank-4 verified per pass.
__host__ __device__ constexpr int sigf(int v) { return v ^ ((v >> 4) & 15); }
// slot of logical label n at epoch k (k CNOT layers folded): slot = sig(m)
__host__ __device__ constexpr int TkF(int v, int k) { return sigf(gkf(v, k)); }

__device__ __forceinline__ v2f cmul(v2f a, v2f b) {
    v2f r; r.x = a.x * b.x - a.y * b.y; r.y = a.x * b.y + a.y * b.x; return r;
}
__device__ __forceinline__ void gate_pair(v2f& a0, v2f& a1, float c, float s) {
    v2f t0 = a0, t1 = a1;
    a0 = c * t0 - s * t1;
    a1 = s * t0 + c * t1;
}
template<int PB>
__device__ __forceinline__ void gate16(v2f (&a)[16], float c, float s) {
    #pragma unroll
    for (int j0 = 0; j0 < 16; ++j0) {
        if (j0 & PB) continue;
        gate_pair(a[j0], a[j0 | PB], c, s);
    }
}
template<int K, int OSH>
__device__ __forceinline__ void ld16(const char* bufc, int sb8, v2f (&a)[16]) {
    #pragma unroll
    for (int j = 0; j < 16; ++j)
        a[j] = *(const v2f*)(bufc + (sb8 ^ (TkF(j << OSH, K) << 3)));
}
template<int K, int OSH>
__device__ __forceinline__ void st16(char* bufc, int sb8, const v2f (&a)[16]) {
    #pragma unroll
    for (int j = 0; j < 16; ++j)
        *(v2f*)(bufc + (sb8 ^ (TkF(j << OSH, K) << 3))) = a[j];
}

// wave64 sum on the VALU pipe (DPP row ops), result valid in lane 63
__device__ __forceinline__ float wave64_sum(float v) {
    v += __int_as_float(__builtin_amdgcn_update_dpp(0, __float_as_int(v), 0x111, 0xf, 0xf, true));
    v += __int_as_float(__builtin_amdgcn_update_dpp(0, __float_as_int(v), 0x112, 0xf, 0xf, true));
    v += __int_as_float(__builtin_amdgcn_update_dpp(0, __float_as_int(v), 0x114, 0xf, 0xf, true));
    v += __int_as_float(__builtin_amdgcn_update_dpp(0, __float_as_int(v), 0x118, 0xf, 0xf, true));
    v += __int_as_float(__builtin_amdgcn_update_dpp(0, __float_as_int(v), 0x142, 0xa, 0xf, false));
    v += __int_as_float(__builtin_amdgcn_update_dpp(0, __float_as_int(v), 0x143, 0xc, 0xf, false));
    return v;
}

__global__ __launch_bounds__(BLK, 2)
void qsim_kernel(const float* __restrict__ x,
                 const float* __restrict__ rys,
                 float* __restrict__ out) {
    __shared__ __align__(16) v2f buf[DIM];           // 32 KB, slot = sig(m) forever
    __shared__ float cr[4 * NQ], sr[4 * NQ];
    __shared__ v2f fac[NQ][2];                       // init factors (d0 RY absorbed)
    __shared__ float zred[4][NQ];

    const int b = blockIdx.x;
    const int t = threadIdx.x;                       // 8 bits
    char* bufc = (char*)buf;

    if (t < 4 * NQ) {
        float th = 0.5f * rys[t];
        cr[t] = cosf(th); sr[t] = sinf(th);
    }
    if (t >= 64 && t < 64 + NQ) {
        int q = t - 64;
        float xh = 0.5f * x[b * NQ + q];
        float cx = cosf(xh), sx = sinf(xh);
        float th = 0.5f * rys[q];                    // layer-0 RY absorbed
        float c0 = cosf(th), s0 = sinf(th);
        int p = NQ - 1 - q;                          // bit position of qubit q
        fac[p][0] = v2f{c0 * cx,  s0 * sx};          // (RY·RX)|0>, bit=0
        fac[p][1] = v2f{s0 * cx, -c0 * sx};          // bit=1
    }
    __syncthreads();

    // base embeddings (logical-label base per pass family)
    const int nbB = (t & 15) | (((t >> 4) & 15) << 8);             // B: bits{0-3,8-11}
    const int nbA7 = ((t & 3) << 4) | (((t >> 2) & 15) << 8)
                   | (((t >> 6) & 3) << 6);                        // P7 lane fix

    // ---- P0: build product state (n1 coords), pregate L1 q3-0, store ----
    {
        v2f a[16];
        const int Mb = t ^ (t >> 1);                 // m bits 0..7 (bit7 = t7)
        v2f P = fac[0][Mb & 1];
        #pragma unroll
        for (int p = 1; p < 7; ++p) P = cmul(P, fac[p][(Mb >> p) & 1]);
        const int b7 = (Mb >> 7) & 1;
        v2f E = cmul(P, fac[7][b7]);                 // register j even
        v2f O = cmul(P, fac[7][b7 ^ 1]);             // register j odd
        v2f L4[4], H4[4];
        #pragma unroll
        for (int v = 0; v < 4; ++v) {
            L4[v] = cmul(fac[8][v & 1],  fac[9][(v >> 1) & 1]);
            H4[v] = cmul(fac[10][v & 1], fac[11][(v >> 1) & 1]);
        }
        #pragma unroll
        for (int j = 0; j < 16; ++j) {
            const int gv = (j ^ (j >> 1)) & 15;      // m bits 8-11 of this register
            a[j] = cmul((j & 1) ? O : E, cmul(L4[gv & 3], H4[(gv >> 2) & 3]));
        }
        gate16<1>(a, cr[15], sr[15]);                // L1 q3 (n1 bit 8)
        gate16<2>(a, cr[14], sr[14]);                // q2
        gate16<4>(a, cr[13], sr[13]);                // q1
        gate16<8>(a, cr[12], sr[12]);                // q0
        st16<1, 8>(bufc, TkF(t, 1) << 3, a);
    }
    __syncthreads();

    #define GATE_PASS(K, NB, OSH, I0, I1, I2, I3)                 \
    {                                                             \
        const int sb8 = TkF(NB, K) << 3;                          \
        v2f a[16];                                                \
        ld16<K, OSH>(bufc, sb8, a);                               \
        gate16<1>(a, cr[I0], sr[I0]);                             \
        gate16<2>(a, cr[I1], sr[I1]);                             \
        gate16<4>(a, cr[I2], sr[I2]);                             \
        gate16<8>(a, cr[I3], sr[I3]);                             \
        st16<K, OSH>(bufc, sb8, a);                               \
    }                                                             \
    __syncthreads();

    GATE_PASS(1, (t << 4), 0, 23, 22, 21, 20)   // P1: L1 q11-8
    GATE_PASS(1, nbB,      4, 19, 18, 17, 16)   // P2: L1 q7-4
    GATE_PASS(2, t,        8, 27, 26, 25, 24)   // P3: relabel2 + L2 q3-0
    GATE_PASS(2, (t << 4), 0, 35, 34, 33, 32)   // P4: L2 q11-8
    GATE_PASS(2, nbB,      4, 31, 30, 29, 28)   // P5: L2 q7-4
    GATE_PASS(3, t,        8, 39, 38, 37, 36)   // P6: relabel3 + L3 q3-0
    GATE_PASS(3, nbA7,     0, 47, 46, 45, 44)   // P7: L3 q11-8
    #undef GATE_PASS

    // ---- P8: L3 q7-4 + relabel4 (labels only) + Z, no store ----
    {
        const int sb8 = TkF(nbB, 3) << 3;
        v2f a[16];
        ld16<3, 4>(bufc, sb8, a);
        gate16<1>(a, cr[43], sr[43]);
        gate16<2>(a, cr[42], sr[42]);
        gate16<4>(a, cr[41], sr[41]);
        gate16<8>(a, cr[40], sr[40]);

        float zacc[NQ];
        #pragma unroll
        for (int q = 0; q < NQ; ++q) zacc[q] = 0.0f;
        #pragma unroll
        for (int j = 0; j < 16; ++j) {
            const int nc = igrayc(j << 4);           // compile-time n4 offset
            const float pr = a[j].x * a[j].x + a[j].y * a[j].y;
            #pragma unroll
            for (int q = 0; q < NQ; ++q)
                zacc[q] += ((nc >> (NQ - 1 - q)) & 1) ? -pr : pr;
        }
        const int R = igrayc(nbB);                   // runtime n4 base
        #pragma unroll
        for (int q = 0; q < NQ; ++q) {
            float v = ((R >> (NQ - 1 - q)) & 1) ? -zacc[q] : zacc[q];
            v = wave64_sum(v);
            if ((t & 63) == 63) zred[t >> 6][q] = v;
        }
    }
    __syncthreads();
    if (t < NQ)
        out[b * NQ + t] = zred[0][t] + zred[1][t] + zred[2][t] + zred[3][t];
}

extern "C" void kernel_launch(void* const* d_in, const int* in_sizes, int n_in,
                              void* d_out, int out_size, void* d_ws, size_t ws_size,
                              hipStream_t stream) {
    const float* x   = (const float*)d_in[0];
    const float* rys = (const float*)d_in[1];
    // d_in[2] (cnot_params) unused by the reference — CNOT takes no params.
    float* out = (float*)d_out;
    qsim_kernel<<<512, BLK, 0, stream>>>(x, rys, out);
}